// Round 11
// baseline (516.141 us; speedup 1.0000x reference)
//
#include <hip/hip_runtime.h>
#include <hip/hip_bf16.h>

#define B_DIM 128
#define S_DIM 64
#define DIN   2048
#define DOUT  2048
#define NLAYERS 64
#define NXCD 8
#define NKS (DIN / 32)                 // 64 K-steps of 32

typedef __bf16 bf16_t;
typedef __attribute__((ext_vector_type(8))) bf16_t bf16x8;
typedef __attribute__((ext_vector_type(4))) float f32x4;

// Parallel rank sort: perm = positions ordered by (layer, s) so duplicate-
// layer positions are adjacent (same XCD under the chunked slot mapping).
__global__ void rank_sort(const int* __restrict__ layer_idx, int* __restrict__ perm) {
    __shared__ int L[S_DIM];
    const int s = threadIdx.x;
    L[s] = layer_idx[s];
    __syncthreads();
    const int mine = L[s];
    int rank = 0;
    #pragma unroll
    for (int t = 0; t < S_DIM; ++t) {
        const int lt = L[t];
        rank += (lt < mine || (lt == mine && t < s)) ? 1 : 0;
    }
    perm[rank] = s;
}

// Streaming pre-pass: x fp32 -> bf16 (halves A request bytes; A then loads
// as one 16B bf16x8 per fragment).
__global__ void convert_x(const float* __restrict__ x, bf16_t* __restrict__ x16) {
    const size_t i = ((size_t)blockIdx.x * 256 + threadIdx.x) * 8;
    f32x4 a = *(const f32x4*)(x + i);
    f32x4 b = *(const f32x4*)(x + i + 4);
    bf16x8 v;
    #pragma unroll
    for (int j = 0; j < 4; ++j) { v[j] = (bf16_t)a[j]; v[j + 4] = (bf16_t)b[j]; }
    *(bf16x8*)(x16 + i) = v;
}

// Direct-to-register GEMM: NO LDS, NO barriers. One wave = one 64x32 output
// tile (4x2 fragments of 16x16x32 MFMA). A/B fragments load straight from
// global (A: bf16x8; B: fp32x8 -> cvt) with a 2-deep named register rotation
// (sets a/b). Waves are fully independent -> phase desync -> TLP hides
// latency; no barrier convoy. Block = 4 waves sharing (s, mq): their A rows
// are L1-resident; XCD-chunked sorted schedule keeps weight panels L2-local.
template <bool XBF16>
__launch_bounds__(256, 3)
__global__ void flex_linear_gemm(const float* __restrict__ x,
                                 const bf16_t* __restrict__ x16,
                                 const float* __restrict__ w,
                                 const int* __restrict__ layer_idx,
                                 const int* __restrict__ perm,
                                 float* __restrict__ out) {
    // ---- XCD-chunked slot mapping (2048 % 8 == 0 -> bijective) ----
    const int orig = blockIdx.x;
    const int xcd  = orig & (NXCD - 1);
    const int slot = orig >> 3;            // 0..255 within XCD
    const int tile = xcd * 256 + slot;     // 0..2047
    const int yy   = tile >> 5;            // sorted-position rank (32 tiles/pos)
    const int sub  = tile & 31;
    const int mq   = sub >> 4;             // 0..1  (which 64-row half of B_DIM)
    const int nbg  = sub & 15;             // 0..15 (128-col group of DOUT)

    const int s     = perm[yy];
    const int layer = layer_idx[s];

    const int wid  = threadIdx.x >> 6;
    const int lane = threadIdx.x & 63;
    const int nb   = nbg * 4 + wid;        // 0..63: this wave's 32-col group
    const int lr   = lane & 15;
    const int lk   = (lane >> 4) * 8;

    // ---- per-lane fragment base pointers ----
    const bf16_t* pa16[4];
    const float*  pa32[4];
    #pragma unroll
    for (int m = 0; m < 4; ++m) {
        const size_t b   = (size_t)(mq * 64 + m * 16 + lr);
        const size_t off = b * (S_DIM * DIN) + (size_t)s * DIN + lk;
        pa16[m] = x16 + off;
        pa32[m] = x + off;
    }
    const float* pb[2];
    #pragma unroll
    for (int n = 0; n < 2; ++n) {
        const size_t orow = (size_t)layer * DOUT + (size_t)(nb * 32 + n * 16 + lr);
        pb[n] = w + orow * DIN + lk;
    }

    f32x4 acc[4][2] = {};

    // ---- 2-deep named register sets (static indexing, rule #20) ----
    bf16x8 Aa[4], Ab[4];
    f32x4  A32a[8], A32b[8];
    f32x4  Ba[4], Bb[4];

    auto load = [&](bf16x8 (&A)[4], f32x4 (&A32)[8], f32x4 (&B)[4], int kb) {
        const int ko = kb * 32;
        #pragma unroll
        for (int m = 0; m < 4; ++m) {
            if constexpr (XBF16) {
                A[m] = *(const bf16x8*)(pa16[m] + ko);
            } else {
                A32[2 * m]     = *(const f32x4*)(pa32[m] + ko);
                A32[2 * m + 1] = *(const f32x4*)(pa32[m] + ko + 4);
            }
        }
        #pragma unroll
        for (int n = 0; n < 2; ++n) {
            B[2 * n]     = *(const f32x4*)(pb[n] + ko);
            B[2 * n + 1] = *(const f32x4*)(pb[n] + ko + 4);
        }
    };
    auto compute = [&](bf16x8 (&A)[4], f32x4 (&A32)[8], f32x4 (&B)[4]) {
        bf16x8 bfr[2];
        #pragma unroll
        for (int n = 0; n < 2; ++n) {
            #pragma unroll
            for (int j = 0; j < 4; ++j) {
                bfr[n][j]     = (bf16_t)B[2 * n][j];
                bfr[n][j + 4] = (bf16_t)B[2 * n + 1][j];
            }
        }
        #pragma unroll
        for (int m = 0; m < 4; ++m) {
            bf16x8 af;
            if constexpr (XBF16) {
                af = A[m];
            } else {
                #pragma unroll
                for (int j = 0; j < 4; ++j) {
                    af[j]     = (bf16_t)A32[2 * m][j];
                    af[j + 4] = (bf16_t)A32[2 * m + 1][j];
                }
            }
            #pragma unroll
            for (int n = 0; n < 2; ++n)
                acc[m][n] = __builtin_amdgcn_mfma_f32_16x16x32_bf16(af, bfr[n], acc[m][n], 0, 0, 0);
        }
    };

    // ---- barrier-free pipelined K loop (2-step unroll, sets a/b) ----
    load(Aa, A32a, Ba, 0);
    for (int kb = 0; kb < NKS; kb += 2) {
        load(Ab, A32b, Bb, kb + 1);        // issue next while a in flight
        compute(Aa, A32a, Ba);             // compiler emits counted vmcnt wait
        if (kb + 2 < NKS) load(Aa, A32a, Ba, kb + 2);
        compute(Ab, A32b, Bb);
    }

    // ---- epilogue: C/D layout col = lane&15, row = (lane>>4)*4 + r ----
    float* Og = out + (size_t)s * DOUT + (size_t)(nb * 32);
    #pragma unroll
    for (int m = 0; m < 4; ++m) {
        const int rb = mq * 64 + m * 16 + (lane >> 4) * 4;
        #pragma unroll
        for (int r = 0; r < 4; ++r) {
            float* orow = Og + (size_t)(rb + r) * (S_DIM * DOUT);
            #pragma unroll
            for (int n = 0; n < 2; ++n)
                __builtin_nontemporal_store(acc[m][n][r], &orow[n * 16 + (lane & 15)]);
        }
    }
}

extern "C" void kernel_launch(void* const* d_in, const int* in_sizes, int n_in,
                              void* d_out, int out_size, void* d_ws, size_t ws_size,
                              hipStream_t stream) {
    const float* x         = (const float*)d_in[0];
    const float* w         = (const float*)d_in[1];
    const int*   layer_idx = (const int*)d_in[2];
    float*       out       = (float*)d_out;

    int*    perm = (int*)d_ws;                        // 64 ints
    bf16_t* x16  = (bf16_t*)((char*)d_ws + 512);      // 32 MB
    const size_t need = 512 + (size_t)B_DIM * S_DIM * DIN * sizeof(bf16_t);

    rank_sort<<<1, S_DIM, 0, stream>>>(layer_idx, perm);

    if (ws_size >= need) {
        convert_x<<<(B_DIM * S_DIM * DIN / 8) / 256, 256, 0, stream>>>(x, x16);
        flex_linear_gemm<true><<<S_DIM * 32, dim3(256), 0, stream>>>(x, x16, w, layer_idx, perm, out);
    } else {
        flex_linear_gemm<false><<<S_DIM * 32, dim3(256), 0, stream>>>(x, x16, w, layer_idx, perm, out);
    }
}

// Round 12
// 223.821 us; speedup vs baseline: 2.3060x; 2.3060x over previous
//
#include <hip/hip_runtime.h>
#include <hip/hip_bf16.h>

#define B_DIM 128
#define S_DIM 64
#define DIN   2048
#define DOUT  2048
#define NLAYERS 64

#define BM 128
#define BN 64
#define BK 64
#define NK (DIN / BK)
#define TPP (DOUT / BN)                 // tiles per position = 32
#define NTILES (S_DIM * TPP)            // 2048
#define NXCD 8

// LDS: A dbuf 2x16KB + B dbuf 2x8KB + 8KB pad = 56KB -> exactly 2 blocks/CU
// (keeps per-XCD active-position window at 2 -> L2-fitting working set).
#define LDS_A 8192                      // elems per A buffer
#define LDS_B 4096                      // elems per B buffer
#define LDS_ELEMS 28672                 // 56 KB
#define A_OFF(b) ((b) * LDS_A)
#define B_OFF(b) (2 * LDS_A + (b) * LDS_B)

typedef __bf16 bf16_t;
typedef __attribute__((ext_vector_type(8))) bf16_t bf16x8;
typedef __attribute__((ext_vector_type(4))) float f32x4;

// Fused pre-pass: x fp32 -> bf16 everywhere; block 0 additionally computes
// the (layer,s) rank-sort permutation (saves one kernel launch).
__global__ void prep(const float* __restrict__ x, bf16_t* __restrict__ x16,
                     const int* __restrict__ layer_idx, int* __restrict__ perm) {
    __shared__ int L[S_DIM];
    if (blockIdx.x == 0) {
        if (threadIdx.x < S_DIM) L[threadIdx.x] = layer_idx[threadIdx.x];
        __syncthreads();
        if (threadIdx.x < S_DIM) {
            const int s = threadIdx.x, mine = L[s];
            int rank = 0;
            #pragma unroll
            for (int t = 0; t < S_DIM; ++t) {
                const int lt = L[t];
                rank += (lt < mine || (lt == mine && t < s)) ? 1 : 0;
            }
            perm[rank] = s;
        }
    }
    const size_t i = ((size_t)blockIdx.x * 256 + threadIdx.x) * 8;
    f32x4 a = *(const f32x4*)(x + i);
    f32x4 b = *(const f32x4*)(x + i + 4);
    bf16x8 v;
    #pragma unroll
    for (int j = 0; j < 4; ++j) { v[j] = (bf16_t)a[j]; v[j + 4] = (bf16_t)b[j]; }
    *(bf16x8*)(x16 + i) = v;
}

// Barrier WITHOUT vmcnt drain: __syncthreads compiles to
// s_waitcnt vmcnt(0) lgkmcnt(0) + s_barrier, force-draining the in-flight
// prefetch every K-step (the structural ~20% stall). We only need LDS
// ordering at the barrier; global loads are read-only and may span it.
// The compiler still emits COUNTED vmcnt waits before the staged registers
// are consumed, so prefetched loads get a full K-step of flight.
__device__ __forceinline__ void lgkm_barrier() {
    __builtin_amdgcn_sched_barrier(0);
    asm volatile("s_waitcnt lgkmcnt(0)" ::: "memory");
    __builtin_amdgcn_sched_barrier(0);
    __builtin_amdgcn_s_barrier();
    __builtin_amdgcn_sched_barrier(0);
}

// 128x64 tile/block; LDS double-buffer; ONE lgkm-only barrier per K-step;
// 2-deep issue distance -> loads fly a full K-step, never force-drained.
template <bool XBF16>
__launch_bounds__(256, 2)
__global__ void flex_linear_gemm(const float* __restrict__ x,
                                 const bf16_t* __restrict__ x16,
                                 const float* __restrict__ w,
                                 const int* __restrict__ layer_idx,
                                 const int* __restrict__ perm,
                                 float* __restrict__ out) {
    __shared__ bf16_t lds[LDS_ELEMS];

    // ---- XCD-chunked swizzle (2048 % 8 == 0 -> bijective) ----
    const int orig = blockIdx.x;
    const int xcd  = orig & (NXCD - 1);
    const int slot = orig >> 3;                  // 0..255 within XCD
    const int tile = xcd * (NTILES / NXCD) + slot;
    const int yy   = tile >> 5;                  // sorted-position rank
    const int nb   = tile & 31;                  // output column block

    const int s  = perm[yy];
    const int layer = layer_idx[s];

    const float* Bg = w + (size_t)layer * (size_t)(DOUT * DIN) + (size_t)(nb * BN) * DIN;

    const int tid  = threadIdx.x;
    const int lane = tid & 63;
    const int wave = tid >> 6;
    const int wr = (wave >> 1) * 64;    // M offset (0/64)
    const int wc = (wave & 1) * 32;     // N offset (0/32)
    const int lrow = lane & 15;
    const int lk   = (lane >> 4) * 8;

    // ---- hoisted addresses ----
    int offWA[4], offWB[2];
    const float*  pA[4];
    const bf16_t* pA16[4];
    const float*  pB[2];
    #pragma unroll
    for (int i = 0; i < 4; ++i) {
        const int c   = tid + 256 * i;
        const int row = c >> 3;              // 0..127 (b index)
        const int kc8 = (c & 7) * 8;
        offWA[i] = (row * BK + kc8) ^ ((row & 7) << 3);
        const size_t aoff = (size_t)row * (S_DIM * DIN) + (size_t)s * DIN + kc8;
        pA[i]   = x   + aoff;
        pA16[i] = x16 + aoff;
    }
    #pragma unroll
    for (int i = 0; i < 2; ++i) {
        const int c   = tid + 256 * i;
        const int row = c >> 3;              // 0..63 (o index within tile)
        const int kc8 = (c & 7) * 8;
        offWB[i] = (row * BK + kc8) ^ ((row & 7) << 3);
        pB[i] = Bg + (size_t)row * DIN + kc8;
    }
    int offA[2][4], offB[2][2];
    #pragma unroll
    for (int kk = 0; kk < 2; ++kk) {
        #pragma unroll
        for (int m = 0; m < 4; ++m) {
            const int ra = wr + m * 16 + lrow;
            offA[kk][m] = (ra * BK + kk * 32 + lk) ^ ((ra & 7) << 3);
        }
        #pragma unroll
        for (int n = 0; n < 2; ++n) {
            const int rb = wc + n * 16 + lrow;
            offB[kk][n] = (rb * BK + kk * 32 + lk) ^ ((rb & 7) << 3);
        }
    }

    bf16x8 RA16[4];           // in-flight A (bf16 path)
    f32x4  RA[8];             // in-flight A (fp32 fallback)
    f32x4  RB[4];             // in-flight B fp32
    f32x4  acc[4][2] = {};

    auto issue = [&](int kb) {
        const int koff = kb * BK;
        #pragma unroll
        for (int i = 0; i < 4; ++i) {
            if constexpr (XBF16) {
                RA16[i] = *(const bf16x8*)(pA16[i] + koff);
            } else {
                const float* a = pA[i] + koff;
                RA[2 * i]     = *(const f32x4*)a;
                RA[2 * i + 1] = *(const f32x4*)(a + 4);
            }
        }
        #pragma unroll
        for (int i = 0; i < 2; ++i) {
            const float* b = pB[i] + koff;
            RB[2 * i]     = *(const f32x4*)b;
            RB[2 * i + 1] = *(const f32x4*)(b + 4);
        }
    };
    auto cvt_write = [&](int buf) {
        bf16_t* Al = &lds[A_OFF(buf)];
        bf16_t* Bl = &lds[B_OFF(buf)];
        #pragma unroll
        for (int i = 0; i < 4; ++i) {
            if constexpr (XBF16) {
                *(bf16x8*)&Al[offWA[i]] = RA16[i];
            } else {
                bf16x8 va;
                #pragma unroll
                for (int j = 0; j < 4; ++j) {
                    va[j]     = (bf16_t)RA[2 * i][j];
                    va[j + 4] = (bf16_t)RA[2 * i + 1][j];
                }
                *(bf16x8*)&Al[offWA[i]] = va;
            }
        }
        #pragma unroll
        for (int i = 0; i < 2; ++i) {
            bf16x8 vb;
            #pragma unroll
            for (int j = 0; j < 4; ++j) {
                vb[j]     = (bf16_t)RB[2 * i][j];
                vb[j + 4] = (bf16_t)RB[2 * i + 1][j];
            }
            *(bf16x8*)&Bl[offWB[i]] = vb;
        }
    };
    auto compute = [&](int buf) {
        const bf16_t* Al = &lds[A_OFF(buf)];
        const bf16_t* Bl = &lds[B_OFF(buf)];
        #pragma unroll
        for (int kk = 0; kk < 2; ++kk) {
            bf16x8 af[4], bfr[2];
            #pragma unroll
            for (int m = 0; m < 4; ++m) af[m]  = *(const bf16x8*)&Al[offA[kk][m]];
            #pragma unroll
            for (int n = 0; n < 2; ++n) bfr[n] = *(const bf16x8*)&Bl[offB[kk][n]];
            #pragma unroll
            for (int m = 0; m < 4; ++m)
                #pragma unroll
                for (int n = 0; n < 2; ++n)
                    acc[m][n] = __builtin_amdgcn_mfma_f32_16x16x32_bf16(af[m], bfr[n], acc[m][n], 0, 0, 0);
        }
    };

    // ---- dbuf pipeline: ONE lgkm-only barrier per K-step, no vmcnt drain.
    // Loads for tile k+1 (issued in iter k-1) fly a FULL K-step; the counted
    // vmcnt wait the compiler emits inside cvt_write is the only load wait.
    issue(0);
    cvt_write(0);                    // counted wait on k=0 loads (once)
    issue(1);                        // k=1 loads fly across iter 0
    lgkm_barrier();                  // buf0 writes visible
    for (int kb = 0; kb < NK; ++kb) {
        compute(kb & 1);
        if (kb + 1 < NK) cvt_write((kb + 1) & 1);   // other buffer: safe after barrier
        if (kb + 2 < NK) issue(kb + 2);             // 2-deep prefetch
        lgkm_barrier();              // ds ordering only; loads keep flying
    }

    // ---- epilogue (nt stores: out never re-read; keep L2 for x/w) ----
    float* Og = out + (size_t)s * DOUT + (size_t)(nb * BN);
    #pragma unroll
    for (int m = 0; m < 4; ++m) {
        const int rb = wr + m * 16 + (lane >> 4) * 4;
        #pragma unroll
        for (int r = 0; r < 4; ++r) {
            float* orow = Og + (size_t)(rb + r) * (S_DIM * DOUT);
            #pragma unroll
            for (int n = 0; n < 2; ++n)
                __builtin_nontemporal_store(acc[m][n][r], &orow[wc + n * 16 + (lane & 15)]);
        }
    }
}

extern "C" void kernel_launch(void* const* d_in, const int* in_sizes, int n_in,
                              void* d_out, int out_size, void* d_ws, size_t ws_size,
                              hipStream_t stream) {
    const float* x         = (const float*)d_in[0];
    const float* w         = (const float*)d_in[1];
    const int*   layer_idx = (const int*)d_in[2];
    float*       out       = (float*)d_out;

    int*    perm = (int*)d_ws;                        // 64 ints
    bf16_t* x16  = (bf16_t*)((char*)d_ws + 512);      // 32 MB
    const size_t need = 512 + (size_t)B_DIM * S_DIM * DIN * sizeof(bf16_t);

    if (ws_size >= need) {
        prep<<<(B_DIM * S_DIM * DIN / 8) / 256, 256, 0, stream>>>(x, x16, layer_idx, perm);
        flex_linear_gemm<true><<<NTILES, dim3(256), 0, stream>>>(x, x16, w, layer_idx, perm, out);
    } else {
        prep<<<(B_DIM * S_DIM * DIN / 8) / 256, 256, 0, stream>>>(x, x16, layer_idx, perm);
        flex_linear_gemm<false><<<NTILES, dim3(256), 0, stream>>>(x, x16, w, layer_idx, perm, out);
    }
}